// Round 1
// baseline (224.849 us; speedup 1.0000x reference)
//
#include <hip/hip_runtime.h>

// Problem constants (fixed by reference):
#define BB 64
#define SS 512
#define HH 768
#define LL 32
#define DD 1536   // 2*H
#define MM 2048   // B*L rows

// ---------------------------------------------------------------------------
// Kernel 1: logits[i] = b_out (atomic-accumulated later)
// ---------------------------------------------------------------------------
__global__ void init_logits(float* __restrict__ out, const float* __restrict__ b_out) {
    int i = blockIdx.x * blockDim.x + threadIdx.x;
    if (i < MM) out[i] = b_out[0];
}

// ---------------------------------------------------------------------------
// Kernel 2: build clause_h rows in ws: row r=(b*L+l) -> [mean(768) | cls(768)]
// One block per row, 256 threads, 3 dims/thread. Coalesced reads/writes.
// ---------------------------------------------------------------------------
__global__ __launch_bounds__(256)
void build_clause(const float* __restrict__ seq, const int* __restrict__ pos,
                  float* __restrict__ ch) {
    int row = blockIdx.x;
    int b = row >> 5;      // row / 32
    int l = row & 31;      // row % 32
    const int* pb = pos + b * (LL + 1);
    int start = pb[l] + 1;
    int end   = pb[l + 1] + 1;
    if (l == LL - 1) end += 1;          // last clause also takes the SEP token
    float inv = 1.0f / (float)(end - start);
    const float* base = seq + (size_t)b * SS * HH;
    int h = threadIdx.x;                // 0..255
    float a0 = 0.f, a1 = 0.f, a2 = 0.f;
    for (int t = start; t < end; ++t) {
        const float* p = base + (size_t)t * HH;
        a0 += p[h]; a1 += p[h + 256]; a2 += p[h + 512];
    }
    float* o = ch + (size_t)row * DD;
    o[h]        = a0 * inv;
    o[h + 256]  = a1 * inv;
    o[h + 512]  = a2 * inv;
    o[HH + h]        = base[h];         // CLS = token 0
    o[HH + h + 256]  = base[h + 256];
    o[HH + h + 512]  = base[h + 512];
}

// ---------------------------------------------------------------------------
// Kernel 3: pooled = tanh(clause_h @ W_pool^T + b_pool); logits += pooled@W_out
// Tiled f32 GEMM: BM=BN=64, BK=16, 256 threads, 4x4 micro-tile per thread.
// Epilogue: per-row partial dot over this block's 64 cols, 16-lane shfl
// reduce, one atomicAdd per row.
// ---------------------------------------------------------------------------
#define Bb 64   // BM
#define Bn 64   // BN
#define Bk 16   // BK

__global__ __launch_bounds__(256)
void gemm_pool(const float* __restrict__ ch,   // [MM][DD]
               const float* __restrict__ Wp,   // [DD][DD] (row n = B[n][k])
               const float* __restrict__ bp,   // [DD]
               const float* __restrict__ Wo,   // [DD]
               float* __restrict__ out) {      // [MM]
    __shared__ float As[Bb][Bk + 1];   // +1 pad: kill 4-way bank conflict
    __shared__ float Bs[Bk][Bn + 1];   // stored transposed [k][n]
    const int bm = blockIdx.x;         // 0..31
    const int bn = blockIdx.y;         // 0..23
    const int tid = threadIdx.x;
    const int ty = tid >> 4;           // 0..15  -> rows ty*4..ty*4+3
    const int tx = tid & 15;           // 0..15  -> cols tx*4..tx*4+3

    // cooperative load indices: 64 rows x 16 k, float4 per thread
    const int lr = tid >> 2;           // 0..63
    const int lk = (tid & 3) * 4;      // 0,4,8,12
    const float* Arow = ch + (size_t)(bm * Bb + lr) * DD + lk;
    const float* Brow = Wp + (size_t)(bn * Bn + lr) * DD + lk;

    float acc[4][4] = {};

    for (int k0 = 0; k0 < DD; k0 += Bk) {
        float4 av = *(const float4*)(Arow + k0);
        float4 bv = *(const float4*)(Brow + k0);
        As[lr][lk + 0] = av.x; As[lr][lk + 1] = av.y;
        As[lr][lk + 2] = av.z; As[lr][lk + 3] = av.w;
        Bs[lk + 0][lr] = bv.x; Bs[lk + 1][lr] = bv.y;
        Bs[lk + 2][lr] = bv.z; Bs[lk + 3][lr] = bv.w;
        __syncthreads();
        #pragma unroll
        for (int k = 0; k < Bk; ++k) {
            float a0 = As[ty * 4 + 0][k];
            float a1 = As[ty * 4 + 1][k];
            float a2 = As[ty * 4 + 2][k];
            float a3 = As[ty * 4 + 3][k];
            float b0 = Bs[k][tx * 4 + 0];
            float b1 = Bs[k][tx * 4 + 1];
            float b2 = Bs[k][tx * 4 + 2];
            float b3 = Bs[k][tx * 4 + 3];
            acc[0][0] += a0 * b0; acc[0][1] += a0 * b1; acc[0][2] += a0 * b2; acc[0][3] += a0 * b3;
            acc[1][0] += a1 * b0; acc[1][1] += a1 * b1; acc[1][2] += a1 * b2; acc[1][3] += a1 * b3;
            acc[2][0] += a2 * b0; acc[2][1] += a2 * b1; acc[2][2] += a2 * b2; acc[2][3] += a2 * b3;
            acc[3][0] += a3 * b0; acc[3][1] += a3 * b1; acc[3][2] += a3 * b2; acc[3][3] += a3 * b3;
        }
        __syncthreads();
    }

    // epilogue: tanh + bias, dot with W_out over this block's columns
    const int ncol = bn * Bn + tx * 4;
    const float w0 = Wo[ncol + 0], w1 = Wo[ncol + 1], w2 = Wo[ncol + 2], w3 = Wo[ncol + 3];
    const float p0 = bp[ncol + 0], p1 = bp[ncol + 1], p2 = bp[ncol + 2], p3 = bp[ncol + 3];
    #pragma unroll
    for (int i = 0; i < 4; ++i) {
        float v = tanhf(acc[i][0] + p0) * w0
                + tanhf(acc[i][1] + p1) * w1
                + tanhf(acc[i][2] + p2) * w2
                + tanhf(acc[i][3] + p3) * w3;
        // reduce across the 16 tx lanes (contiguous lanes within a wave)
        #pragma unroll
        for (int off = 8; off; off >>= 1) v += __shfl_xor(v, off, 16);
        if (tx == 0) atomicAdd(&out[bm * Bb + ty * 4 + i], v);
    }
}

// ---------------------------------------------------------------------------
extern "C" void kernel_launch(void* const* d_in, const int* in_sizes, int n_in,
                              void* d_out, int out_size, void* d_ws, size_t ws_size,
                              hipStream_t stream) {
    const float* seq   = (const float*)d_in[0];  // [B,S,H]
    // d_in[1] = context_h (unused by reference)
    const float* Wp    = (const float*)d_in[2];  // [D,D]
    const float* bp    = (const float*)d_in[3];  // [D]
    const float* Wo    = (const float*)d_in[4];  // [D]
    const float* bo    = (const float*)d_in[5];  // scalar
    const int*   pos   = (const int*)d_in[6];    // [B,L+1]
    // d_in[7] = doc_lens (unused by reference)
    float* out = (float*)d_out;                  // [B,L] = 2048
    float* ch  = (float*)d_ws;                   // [MM][DD] f32 = 12.6 MB

    init_logits<<<(MM + 255) / 256, 256, 0, stream>>>(out, bo);
    build_clause<<<MM, 256, 0, stream>>>(seq, pos, ch);
    dim3 grid(MM / Bb, DD / Bn);
    gemm_pool<<<grid, 256, 0, stream>>>(ch, Wp, bp, Wo, out);
}

// Round 2
// 68.268 us; speedup vs baseline: 3.2936x; 3.2936x over previous
//
#include <hip/hip_runtime.h>
#include <hip/hip_bf16.h>

// Problem constants (fixed by reference):
#define BB 64
#define SS 512
#define HH 768
#define LL 32
#define DD 1536   // 2*H
#define MM 2048   // B*L rows
#define KK DD     // GEMM K

typedef float f32x4 __attribute__((ext_vector_type(4)));
typedef short bf16x8 __attribute__((ext_vector_type(8)));

__device__ __forceinline__ unsigned short f2bf(float x) {
    union { float f; unsigned u; } v; v.f = x;
    unsigned r = v.u + 0x7fff + ((v.u >> 16) & 1);   // round-to-nearest-even
    return (unsigned short)(r >> 16);
}

__device__ __forceinline__ void gload16(const unsigned short* g, unsigned short* l) {
    // async global->LDS, 16B per lane; LDS dest = wave-uniform base + lane*16
    __builtin_amdgcn_global_load_lds(
        (const __attribute__((address_space(1))) void*)g,
        (__attribute__((address_space(3))) void*)l, 16, 0, 0);
}

// ---------------------------------------------------------------------------
// Kernel 1: logits[i] = b_out (atomic-accumulated later)
// ---------------------------------------------------------------------------
__global__ void init_logits(float* __restrict__ out, const float* __restrict__ b_out) {
    int i = blockIdx.x * blockDim.x + threadIdx.x;
    if (i < MM) out[i] = b_out[0];
}

// ---------------------------------------------------------------------------
// Kernel 2: build clause_h rows (bf16) in ws: row r=(b*L+l) -> [mean | cls]
// One block per row, 256 threads, 3 dims/thread. f32 accumulate, bf16 store.
// ---------------------------------------------------------------------------
__global__ __launch_bounds__(256)
void build_clause(const float* __restrict__ seq, const int* __restrict__ pos,
                  unsigned short* __restrict__ ch) {
    int row = blockIdx.x;
    int b = row >> 5;      // row / 32
    int l = row & 31;      // row % 32
    const int* pb = pos + b * (LL + 1);
    int start = pb[l] + 1;
    int end   = pb[l + 1] + 1;
    if (l == LL - 1) end += 1;          // last clause also takes the SEP token
    float inv = 1.0f / (float)(end - start);
    const float* base = seq + (size_t)b * SS * HH;
    int h = threadIdx.x;                // 0..255
    float a0 = 0.f, a1 = 0.f, a2 = 0.f;
    for (int t = start; t < end; ++t) {
        const float* p = base + (size_t)t * HH;
        a0 += p[h]; a1 += p[h + 256]; a2 += p[h + 512];
    }
    unsigned short* o = ch + (size_t)row * DD;
    o[h]        = f2bf(a0 * inv);
    o[h + 256]  = f2bf(a1 * inv);
    o[h + 512]  = f2bf(a2 * inv);
    o[HH + h]        = f2bf(base[h]);   // CLS = token 0
    o[HH + h + 256]  = f2bf(base[h + 256]);
    o[HH + h + 512]  = f2bf(base[h + 512]);
}

// ---------------------------------------------------------------------------
// Kernel 3: W_pool f32 -> bf16 (one-time per call, 2.36M elems, 4/thread)
// ---------------------------------------------------------------------------
__global__ __launch_bounds__(256)
void convert_wp(const float* __restrict__ Wp, unsigned short* __restrict__ wb) {
    int i = (blockIdx.x * blockDim.x + threadIdx.x) * 4;
    float4 v = *(const float4*)(Wp + i);
    ushort4 o;
    o.x = f2bf(v.x); o.y = f2bf(v.y); o.z = f2bf(v.z); o.w = f2bf(v.w);
    *(ushort4*)(wb + i) = o;
}

// ---------------------------------------------------------------------------
// Kernel 4: bf16 MFMA GEMM  C[2048][1536] = A @ Wp^T, fused tanh/W_out epilogue
// 128x128 tile, BK=32, 4 waves (2x2), 16x16x32 bf16 MFMA, 4x4 frags/wave.
// global_load_lds width-16 staging, 2-phase double buffer (prefetch overlaps
// MFMA; one barrier per K-step drains vmcnt).
// ---------------------------------------------------------------------------
__global__ __launch_bounds__(256)
void gemm_mfma(const unsigned short* __restrict__ A,   // [MM][KK] bf16
               const unsigned short* __restrict__ Bm,  // [DD][KK] bf16 (W_pool)
               const float* __restrict__ bp,           // [DD]
               const float* __restrict__ Wo,           // [DD]
               float* __restrict__ out) {              // [MM]
    __shared__ unsigned short As[2][128 * 32];  // 2 x 8 KB
    __shared__ unsigned short Bs[2][128 * 32];
    const int tid  = threadIdx.x;
    const int wid  = tid >> 6;
    const int lane = tid & 63;
    const int wrow = wid >> 1, wcol = wid & 1;
    const int brow = blockIdx.x * 128;
    const int bcol = blockIdx.y * 128;

    // staging: thread t loads A row (t/4 + i*64), k-bytes [(t%4)*16 .. +16)
    const int srow = tid >> 2;             // 0..63
    const int scol = (tid & 3) * 8;        // element offset 0,8,16,24
    const unsigned short* gA0 = A  + (size_t)(brow + srow)      * KK + scol;
    const unsigned short* gA1 = A  + (size_t)(brow + srow + 64) * KK + scol;
    const unsigned short* gB0 = Bm + (size_t)(bcol + srow)      * KK + scol;
    const unsigned short* gB1 = Bm + (size_t)(bcol + srow + 64) * KK + scol;

#define STAGE(buf, k0) do {                                   \
        gload16(gA0 + (k0), &As[(buf)][wid * 512]);           \
        gload16(gA1 + (k0), &As[(buf)][2048 + wid * 512]);    \
        gload16(gB0 + (k0), &Bs[(buf)][wid * 512]);           \
        gload16(gB1 + (k0), &Bs[(buf)][2048 + wid * 512]);    \
    } while (0)

    f32x4 acc[4][4] = {};
    const int koff = (lane >> 4) * 8;
    const int fr   = lane & 15;

    STAGE(0, 0);
    int cur = 0;
    const int NT = KK / 32;                // 48
    for (int t = 0; t < NT; ++t) {
        __syncthreads();                   // drains vmcnt: buf[cur] ready
        if (t + 1 < NT) STAGE(cur ^ 1, (t + 1) * 32);  // prefetch overlaps MFMA
        bf16x8 af[4], bfr[4];
        #pragma unroll
        for (int f = 0; f < 4; ++f) {
            int ar = wrow * 64 + f * 16 + fr;
            af[f]  = *(const bf16x8*)&As[cur][ar * 32 + koff];
            int br = wcol * 64 + f * 16 + fr;
            bfr[f] = *(const bf16x8*)&Bs[cur][br * 32 + koff];
        }
        #pragma unroll
        for (int m = 0; m < 4; ++m)
            #pragma unroll
            for (int n = 0; n < 4; ++n)
                acc[m][n] = __builtin_amdgcn_mfma_f32_16x16x32_bf16(
                    af[m], bfr[n], acc[m][n], 0, 0, 0);
        cur ^= 1;
    }
#undef STAGE

    // epilogue: C/D layout col=lane&15, row=(lane>>4)*4+reg  (m89-verified)
    const int rg = (lane >> 4) * 4;
    #pragma unroll
    for (int m = 0; m < 4; ++m) {
        float vsum[4] = {0.f, 0.f, 0.f, 0.f};
        #pragma unroll
        for (int n = 0; n < 4; ++n) {
            int col = bcol + wcol * 64 + n * 16 + fr;
            float w  = Wo[col];
            float pb = bp[col];
            #pragma unroll
            for (int r = 0; r < 4; ++r) {
                float x = acc[m][n][r] + pb;
                float th = 1.f - 2.f / (__expf(2.f * x) + 1.f);  // tanh(x)
                vsum[r] += th * w;
            }
        }
        #pragma unroll
        for (int r = 0; r < 4; ++r) {
            float v = vsum[r];
            v += __shfl_xor(v, 1, 16);
            v += __shfl_xor(v, 2, 16);
            v += __shfl_xor(v, 4, 16);
            v += __shfl_xor(v, 8, 16);
            if (fr == 0)
                atomicAdd(&out[brow + wrow * 64 + m * 16 + rg + r], v);
        }
    }
}

// ---------------------------------------------------------------------------
extern "C" void kernel_launch(void* const* d_in, const int* in_sizes, int n_in,
                              void* d_out, int out_size, void* d_ws, size_t ws_size,
                              hipStream_t stream) {
    const float* seq   = (const float*)d_in[0];  // [B,S,H]
    // d_in[1] = context_h (unused by reference)
    const float* Wp    = (const float*)d_in[2];  // [D,D]
    const float* bp    = (const float*)d_in[3];  // [D]
    const float* Wo    = (const float*)d_in[4];  // [D]
    const float* bo    = (const float*)d_in[5];  // scalar
    const int*   pos   = (const int*)d_in[6];    // [B,L+1]
    // d_in[7] = doc_lens (unused by reference)
    float* out = (float*)d_out;                  // [B,L] = 2048

    unsigned short* Abf = (unsigned short*)d_ws;       // [MM][DD] bf16 = 6.29 MB
    unsigned short* Wbf = Abf + (size_t)MM * DD;       // [DD][DD] bf16 = 4.72 MB

    init_logits<<<(MM + 255) / 256, 256, 0, stream>>>(out, bo);
    build_clause<<<MM, 256, 0, stream>>>(seq, pos, Abf);
    convert_wp<<<(DD * DD / 4) / 256, 256, 0, stream>>>(Wp, Wbf);
    dim3 grid(MM / 128, DD / 128);
    gemm_mfma<<<grid, 256, 0, stream>>>(Abf, Wbf, bp, Wo, out);
}

// Round 3
// 61.390 us; speedup vs baseline: 3.6626x; 1.1120x over previous
//
#include <hip/hip_runtime.h>
#include <hip/hip_bf16.h>

// Problem constants (fixed by reference):
#define SS 512
#define HH 768
#define LL 32
#define DD 1536   // 2*H
#define MM 2048   // B*L rows
#define KK DD     // GEMM K
#define NT (KK / 32)   // 48 K-steps

typedef float f32x4 __attribute__((ext_vector_type(4)));
typedef short bf16x8 __attribute__((ext_vector_type(8)));

__device__ __forceinline__ unsigned short f2bf(float x) {
    union { float f; unsigned u; } v; v.f = x;
    unsigned r = v.u + 0x7fff + ((v.u >> 16) & 1);   // round-to-nearest-even
    return (unsigned short)(r >> 16);
}

__device__ __forceinline__ void gload16(const unsigned short* g, unsigned short* l) {
    // async global->LDS, 16B per lane; LDS dest = wave-uniform base + lane*16
    __builtin_amdgcn_global_load_lds(
        (const __attribute__((address_space(1))) void*)g,
        (__attribute__((address_space(3))) void*)l, 16, 0, 0);
}

// ---------------------------------------------------------------------------
// Kernel 1: logits[i] = b_out (atomic-accumulated later)
// ---------------------------------------------------------------------------
__global__ void init_logits(float* __restrict__ out, const float* __restrict__ b_out) {
    int i = blockIdx.x * blockDim.x + threadIdx.x;
    if (i < MM) out[i] = b_out[0];
}

// ---------------------------------------------------------------------------
// Kernel 2: build clause_h rows (bf16): row r=(b*L+l) -> [mean(768) | cls(768)]
// ---------------------------------------------------------------------------
__global__ __launch_bounds__(256)
void build_clause(const float* __restrict__ seq, const int* __restrict__ pos,
                  unsigned short* __restrict__ ch) {
    int row = blockIdx.x;
    int b = row >> 5;
    int l = row & 31;
    const int* pb = pos + b * (LL + 1);
    int start = pb[l] + 1;
    int end   = pb[l + 1] + 1;
    if (l == LL - 1) end += 1;          // last clause also takes the SEP token
    float inv = 1.0f / (float)(end - start);
    const float* base = seq + (size_t)b * SS * HH;
    int h = threadIdx.x;                // 0..255
    float a0 = 0.f, a1 = 0.f, a2 = 0.f;
    for (int t = start; t < end; ++t) {
        const float* p = base + (size_t)t * HH;
        a0 += p[h]; a1 += p[h + 256]; a2 += p[h + 512];
    }
    unsigned short* o = ch + (size_t)row * DD;
    o[h]        = f2bf(a0 * inv);
    o[h + 256]  = f2bf(a1 * inv);
    o[h + 512]  = f2bf(a2 * inv);
    o[HH + h]        = f2bf(base[h]);   // CLS = token 0
    o[HH + h + 256]  = f2bf(base[h + 256]);
    o[HH + h + 512]  = f2bf(base[h + 512]);
}

// ---------------------------------------------------------------------------
// Kernel 3: W_pool f32 -> bf16
// ---------------------------------------------------------------------------
__global__ __launch_bounds__(256)
void convert_wp(const float* __restrict__ Wp, unsigned short* __restrict__ wb) {
    int i = (blockIdx.x * blockDim.x + threadIdx.x) * 4;
    float4 v = *(const float4*)(Wp + i);
    ushort4 o;
    o.x = f2bf(v.x); o.y = f2bf(v.y); o.z = f2bf(v.z); o.w = f2bf(v.w);
    *(ushort4*)(wb + i) = o;
}

// ---------------------------------------------------------------------------
// Kernel 4: bf16 MFMA GEMM, 128x128 tile, 8 waves (4x2, wave tile 32x64),
// 4-deep LDS pipeline with counted vmcnt (never 0 in steady state), raw
// s_barrier, chunk-XOR LDS swizzle (source-side pre-swizzle + read-side XOR).
// Fused epilogue: tanh(acc+b_pool)·W_out, 16-lane shfl reduce, atomicAdd.
// ---------------------------------------------------------------------------
__global__ __launch_bounds__(512, 2)
void gemm_mfma(const unsigned short* __restrict__ A,   // [MM][KK] bf16
               const unsigned short* __restrict__ Bm,  // [DD][KK] bf16
               const float* __restrict__ bp,           // [DD]
               const float* __restrict__ Wo,           // [DD]
               float* __restrict__ out) {              // [MM]
    __shared__ unsigned short As[4][128 * 32];  // 4 x 8 KB
    __shared__ unsigned short Bs[4][128 * 32];  // 4 x 8 KB  (64 KB total)
    const int tid  = threadIdx.x;
    const int wid  = tid >> 6;          // 0..7
    const int lane = tid & 63;
    const int wrow = wid >> 1;          // 0..3 -> 32 rows each
    const int wcol = wid & 1;           // 0..1 -> 64 cols each
    const int brow = blockIdx.x * 128;
    const int bcol = blockIdx.y * 128;

    // staging: 512 threads x one 16B chunk per tile. LDS dest is linear
    // (wave base + lane*16); the SOURCE k-chunk is XOR-swizzled so the LDS
    // image is swizzled (rule #21: inverse-swz source + swz read).
    const int srow   = tid >> 2;                       // 0..127
    const int schunk = (tid & 3) ^ ((tid >> 4) & 3);   // chunk ^ (row>>2)&3
    const unsigned short* gA = A  + (size_t)(brow + srow) * KK + schunk * 8;
    const unsigned short* gB = Bm + (size_t)(bcol + srow) * KK + schunk * 8;

#define STAGE(buf, t) do {                                \
        gload16(gA + (t) * 32, &As[(buf)][wid * 512]);    \
        gload16(gB + (t) * 32, &Bs[(buf)][wid * 512]);    \
    } while (0)

    f32x4 acc[2][4] = {};
    const int fr = lane & 15;
    const int fq = lane >> 4;                 // k-chunk this lane needs
    const int rchunk = (fq ^ (fr >> 2)) * 8;  // swizzled read chunk (elements)
    const int arow0 = (wrow * 32 + fr) * 32 + rchunk;
    const int brow0 = (wcol * 64 + fr) * 32 + rchunk;

    STAGE(0, 0); STAGE(1, 1); STAGE(2, 2);

    for (int t = 0; t < NT; ++t) {
        __builtin_amdgcn_sched_barrier(0);
        if (t < NT - 2)       asm volatile("s_waitcnt vmcnt(4)" ::: "memory");
        else if (t == NT - 2) asm volatile("s_waitcnt vmcnt(2)" ::: "memory");
        else                  asm volatile("s_waitcnt vmcnt(0)" ::: "memory");
        __builtin_amdgcn_s_barrier();
        __builtin_amdgcn_sched_barrier(0);
        if (t + 3 < NT) STAGE((t + 3) & 3, t + 3);   // 3-ahead prefetch
        const unsigned short* as = As[t & 3];
        const unsigned short* bs = Bs[t & 3];
        bf16x8 af[2], bf[4];
        af[0] = *(const bf16x8*)&as[arow0];
        af[1] = *(const bf16x8*)&as[arow0 + 16 * 32];
        #pragma unroll
        for (int n = 0; n < 4; ++n)
            bf[n] = *(const bf16x8*)&bs[brow0 + n * 16 * 32];
        #pragma unroll
        for (int m = 0; m < 2; ++m)
            #pragma unroll
            for (int n = 0; n < 4; ++n)
                acc[m][n] = __builtin_amdgcn_mfma_f32_16x16x32_bf16(
                    af[m], bf[n], acc[m][n], 0, 0, 0);
    }
#undef STAGE

    // epilogue: C/D layout col=lane&15, row=(lane>>4)*4+reg (m89-verified)
    const int rg = fq * 4;
    #pragma unroll
    for (int m = 0; m < 2; ++m) {
        float vsum[4] = {0.f, 0.f, 0.f, 0.f};
        #pragma unroll
        for (int n = 0; n < 4; ++n) {
            int col = bcol + wcol * 64 + n * 16 + fr;
            float w  = Wo[col];
            float pb = bp[col];
            #pragma unroll
            for (int r = 0; r < 4; ++r) {
                float x = acc[m][n][r] + pb;
                float th = 1.f - 2.f / (__expf(2.f * x) + 1.f);  // tanh(x)
                vsum[r] += th * w;
            }
        }
        #pragma unroll
        for (int r = 0; r < 4; ++r) {
            float v = vsum[r];
            v += __shfl_xor(v, 1, 16);
            v += __shfl_xor(v, 2, 16);
            v += __shfl_xor(v, 4, 16);
            v += __shfl_xor(v, 8, 16);
            if (fr == 0)
                atomicAdd(&out[brow + wrow * 32 + m * 16 + rg + r], v);
        }
    }
}

// ---------------------------------------------------------------------------
extern "C" void kernel_launch(void* const* d_in, const int* in_sizes, int n_in,
                              void* d_out, int out_size, void* d_ws, size_t ws_size,
                              hipStream_t stream) {
    const float* seq   = (const float*)d_in[0];  // [B,S,H]
    // d_in[1] = context_h (unused by reference)
    const float* Wp    = (const float*)d_in[2];  // [D,D]
    const float* bp    = (const float*)d_in[3];  // [D]
    const float* Wo    = (const float*)d_in[4];  // [D]
    const float* bo    = (const float*)d_in[5];  // scalar
    const int*   pos   = (const int*)d_in[6];    // [B,L+1]
    // d_in[7] = doc_lens (unused by reference)
    float* out = (float*)d_out;                  // [B,L] = 2048

    unsigned short* Abf = (unsigned short*)d_ws;       // [MM][DD] bf16
    unsigned short* Wbf = Abf + (size_t)MM * DD;       // [DD][DD] bf16

    init_logits<<<(MM + 255) / 256, 256, 0, stream>>>(out, bo);
    build_clause<<<MM, 256, 0, stream>>>(seq, pos, Abf);
    convert_wp<<<(DD * DD / 4) / 256, 256, 0, stream>>>(Wp, Wbf);
    dim3 grid(MM / 128, DD / 128);
    gemm_mfma<<<grid, 512, 0, stream>>>(Abf, Wbf, bp, Wo, out);
}